// Round 1
// 196.827 us; speedup vs baseline: 1.0022x; 1.0022x over previous
//
#include <hip/hip_runtime.h>

// B=16384 bags, HIST=50, K=128, EMB_DIM=3. Three chained linears with no
// activation collapse into one 3x128 affine map (collapse_weights_kernel).
//
// Fused kernel v2: one 64-lane wave per bag, ONE LANE PER ROW.
//   - lane r (r < cnt) loads index eb_input[start+r] (coalesced) and gathers
//     the full 12 B embedding row as a single dwordx3 — 1 VMEM request per
//     row instead of 3 scalar component loads x 4 predicated rounds.
//   - MLP dot: lane k owns x[2k],x[2k+1]; collapsed weights stored transposed
//     and padded as wsT[128][4] so each lane reads them as two float4s.
//   - 6-value (sx,sy,sz,m0,m1,m2) 64-lane butterfly reduction; lanes 0..11
//     write the 12 output columns (coalesced 48 B store per bag).
// Per-wave VMEM lane-slots drop ~390 -> ~110 vs v1; gather requests are
// deduplicated (each row fetched once). Address-path bound -> ~3.5x fewer
// requests.

#define KDIM 128

struct F3 { float x, y, z; };   // 12-byte row; compiles to global_load_dwordx3

// --- Kernel 1: collapse the 3 linear layers -------------------------------
// Output layout (ws):
//   ws[k*4 + o] = Wc[o][k]   for k in [0,128), o in [0,3)   (ws[k*4+3] = pad)
//   ws[512 + o] = bc[o]
__global__ __launch_bounds__(KDIM) void collapse_weights_kernel(
    const float* __restrict__ w0, const float* __restrict__ b0,
    const float* __restrict__ w1, const float* __restrict__ b1,
    const float* __restrict__ w2, const float* __restrict__ b2,
    float* __restrict__ ws)
{
    __shared__ float t[6][KDIM];   // w1 @ w0  (6 x 128)
    __shared__ float tb[6];        // w1 @ b0 + b1

    const int k = threadIdx.x;     // 0..127
    for (int i = 0; i < 6; ++i) {
        float acc = 0.f;
        for (int j = 0; j < 12; ++j)
            acc += w1[i * 12 + j] * w0[j * KDIM + k];
        t[i][k] = acc;
    }
    if (k < 6) {
        float acc = 0.f;
        for (int j = 0; j < 12; ++j)
            acc += w1[k * 12 + j] * b0[j];
        tb[k] = acc + b1[k];
    }
    __syncthreads();

    for (int o = 0; o < 3; ++o) {
        float acc = 0.f;
        for (int i = 0; i < 6; ++i)
            acc += w2[o * 6 + i] * t[i][k];
        ws[k * 4 + o] = acc;       // transposed, padded
    }
    ws[k * 4 + 3] = 0.f;
    if (k == 0) {
        for (int o = 0; o < 3; ++o) {
            float acc = 0.f;
            for (int i = 0; i < 6; ++i)
                acc += w2[o * 6 + i] * tb[i];
            ws[512 + o] = acc + b2[o];
        }
    }
}

// --- Kernel 2: fused embedding-bag mean + collapsed MLP -------------------
__global__ __launch_bounds__(256) void fused_embbag_mlp_kernel(
    const int* __restrict__ eb_input,     // [N] indices (int32)
    const int* __restrict__ eb_offset,    // [B] bag starts
    const float* __restrict__ mlp_input,  // [B, 128]
    const float* __restrict__ emb_weight, // [NUM_EMB, 3]
    const float* __restrict__ ws,         // wsT[128][4], bc[3]
    float* __restrict__ out,              // [B, 12]
    int n_indices, int num_bags)
{
    const int lane = threadIdx.x & 63;
    const int wave = threadIdx.x >> 6;
    const int bag  = blockIdx.x * (blockDim.x >> 6) + wave;
    if (bag >= num_bags) return;

    const int start = eb_offset[bag];
    const int end   = (bag + 1 < num_bags) ? eb_offset[bag + 1] : n_indices;
    const int cnt   = end - start;

    // --- MLP partials (issue first; independent of the gather chain) ------
    // 10M*3 floats = 30M elements -> 32-bit offsets are safe everywhere.
    const float2 x  = *(const float2*)(mlp_input + bag * KDIM + lane * 2);
    const float4 t0 = *(const float4*)(ws + lane * 8);
    const float4 t1 = *(const float4*)(ws + lane * 8 + 4);
    float m0 = x.x * t0.x + x.y * t1.x;
    float m1 = x.x * t0.y + x.y * t1.y;
    float m2 = x.x * t0.z + x.y * t1.z;

    // --- Embedding gather: lane r owns rows start+r, start+r+64, ... ------
    float sx = 0.f, sy = 0.f, sz = 0.f;
    if (lane < cnt) {
        const int idx = eb_input[start + lane];
        const F3 r = *(const F3*)(emb_weight + idx * 3);
        sx = r.x; sy = r.y; sz = r.z;
        // Tail (cnt > 64) — never taken for HIST=50
        for (int p = start + lane + 64; p < end; p += 64) {
            const int i2 = eb_input[p];
            const F3 r2 = *(const F3*)(emb_weight + i2 * 3);
            sx += r2.x; sy += r2.y; sz += r2.z;
        }
    }

    // --- Full-wave butterfly reduction of all 6 partials ------------------
    #pragma unroll
    for (int off = 1; off <= 32; off <<= 1) {
        sx += __shfl_xor(sx, off, 64);
        sy += __shfl_xor(sy, off, 64);
        sz += __shfl_xor(sz, off, 64);
        m0 += __shfl_xor(m0, off, 64);
        m1 += __shfl_xor(m1, off, 64);
        m2 += __shfl_xor(m2, off, 64);
    }

    // --- Epilogue: lanes 0..11 write the 12 columns -----------------------
    if (lane < 12) {
        float v;
        if (lane < 9) {
            const float inv = 1.0f / fmaxf((float)cnt, 1.0f);
            const int cc = lane % 3;
            v = (cc == 0 ? sx : (cc == 1 ? sy : sz)) * inv;
        } else {
            const int cc = lane - 9;
            v = (cc == 0 ? m0 : (cc == 1 ? m1 : m2)) + ws[512 + cc];
        }
        out[bag * 12 + lane] = v;
    }
}

extern "C" void kernel_launch(void* const* d_in, const int* in_sizes, int n_in,
                              void* d_out, int out_size, void* d_ws, size_t ws_size,
                              hipStream_t stream) {
    const int*   eb_input   = (const int*)d_in[0];   // [B*HIST] int32
    const int*   eb_offset  = (const int*)d_in[1];   // [B] int32
    const float* mlp_input  = (const float*)d_in[2]; // [B,128]
    const float* emb_weight = (const float*)d_in[3]; // [10M,3]
    const float* w0 = (const float*)d_in[4];
    const float* b0 = (const float*)d_in[5];
    const float* w1 = (const float*)d_in[6];
    const float* b1 = (const float*)d_in[7];
    const float* w2 = (const float*)d_in[8];
    const float* b2 = (const float*)d_in[9];
    float* out = (float*)d_out;
    float* ws  = (float*)d_ws;   // 515 floats used

    const int n_indices = in_sizes[0];
    const int num_bags  = in_sizes[1];

    collapse_weights_kernel<<<1, KDIM, 0, stream>>>(w0, b0, w1, b1, w2, b2, ws);

    const int waves_per_block = 4;                 // 256 threads
    const int grid = (num_bags + waves_per_block - 1) / waves_per_block;
    fused_embbag_mlp_kernel<<<grid, 256, 0, stream>>>(
        eb_input, eb_offset, mlp_input, emb_weight, ws, out, n_indices, num_bags);
}